// Round 4
// baseline (221.764 us; speedup 1.0000x reference)
//
#include <hip/hip_runtime.h>
#include <hip/hip_bf16.h>
#include <cstddef>

// ---------------------------------------------------------------------------
// AttentionBlock: B=2, H=W=64 (S=4096), C=512, GROUPS=32, fp32 in/out.
// GroupNorm -> qkv -> P = softmax(q k^T / sqrt(C)) -> o = P v -> o@Wp + bp + x
// R10: per-phase diagnostic: QK 46.6us @ MfmaUtil 28.7% = m97-structure
//      ceiling. R11: 256^2 8-phase QK port REGRESSED (51.6us, 25.5%), but
//      FETCH halved (59.7->24.7MB) -> memory side right, schedule wrong:
//      (1) 12 ds_read_b128/wave/phase = 768cy LDS/CU/phase >> 155cy MFMA
//          (no fragment holds, quadrant re-reads);
//      (2) 5x sched_barrier(0)/phase + lgkmcnt(0) drain = m141 order-pinning;
//      (3) 2 barriers/phase where 1 suffices.
// R12: fix k_qk256: Z-order phases (0,0)(0,1)(1,1)(1,0) with register holds
//      (reads 48->24/tile/wave: p0 fa+fbA=12, p1 fbB=4, p2 fa=8, p3 0);
//      ONE s_barrier/phase; no sched_barrier; counted vmcnt(4) at tile
//      boundary only. Stage slot order [A0,B1,B0,A1] re-derived race-free:
//      overwrite-issue >= last-LDS-read + 1 barrier for every slot.
//      Everything else identical to R11.
// ---------------------------------------------------------------------------

typedef __bf16 bf16;
typedef __attribute__((ext_vector_type(8))) __bf16 bf16x8;
typedef __attribute__((ext_vector_type(4))) __bf16 bf16x4;
typedef __attribute__((ext_vector_type(4))) float f32x4;

#define SEQ   4096
#define CCH   512
#define NBAT  2
#define NOMASK 0x7FFFFFFF
#define SMEM_BYTES 32768   // As 16K + Bs 16K; EPI2 reduce reuses As post-loop

// ---------------------------------------------------------------------------
// prep unit: bid<512 GN-stats partials (statsP[bg*16+c]=S, +8+c=SS, race-free)
//            bid in [512,1536) weight transpose-cast; bid==1536 bias pack.
__device__ __forceinline__ void prep_unit(
    char* smem, int bid, const float* __restrict__ x,
    const float* __restrict__ Wq, const float* __restrict__ Wk,
    const float* __restrict__ Wv, const float* __restrict__ Wp,
    const float* __restrict__ bq, const float* __restrict__ bk,
    const float* __restrict__ bv,
    float* __restrict__ statsP, bf16* __restrict__ WqkvT,
    bf16* __restrict__ WpT, float* __restrict__ biasQKV) {
    const int tid = threadIdx.x;
    if (bid < 512) {
        float* red = (float*)smem;            // 8 floats
        int bg = bid >> 3, c = bid & 7;
        int b = bg >> 5, g = bg & 31;
        const float* base = x + (size_t)b * SEQ * CCH + g * 16;
        float s = 0.f, ss = 0.f;
        for (int i = tid; i < 2048; i += 256) {      // 512 spatial x 4 float4
            int sp = c * 512 + (i >> 2), q = i & 3;
            float4 v = *(const float4*)(base + (size_t)sp * CCH + q * 4);
            s  += v.x + v.y + v.z + v.w;
            ss += v.x * v.x + v.y * v.y + v.z * v.z + v.w * v.w;
        }
        #pragma unroll
        for (int o = 32; o > 0; o >>= 1) { s += __shfl_down(s, o); ss += __shfl_down(ss, o); }
        int wave = tid >> 6, lane = tid & 63;
        if (lane == 0) { red[wave] = s; red[4 + wave] = ss; }
        __syncthreads();
        if (tid == 0) {
            statsP[bg * 16 + c]     = red[0] + red[1] + red[2] + red[3];
            statsP[bg * 16 + 8 + c] = red[4] + red[5] + red[6] + red[7];
        }
        __syncthreads();
    } else if (bid < 1536) {
        float (*tile)[33] = (float(*)[33])smem;      // 4224 B
        int w = bid - 512;
        int z = w >> 8, rest = w & 255;
        int k0 = (rest >> 4) * 32, n0 = (rest & 15) * 32;
        const float* W = (z == 0) ? Wq : (z == 1) ? Wk : (z == 2) ? Wv : Wp;
        int tx = tid & 31, ty = tid >> 5;
        #pragma unroll
        for (int i = ty; i < 32; i += 8)
            tile[i][tx] = W[(size_t)(k0 + i) * CCH + n0 + tx];
        __syncthreads();
        bf16* dst = (z < 3) ? (WqkvT + (size_t)z * CCH * CCH) : WpT;
        #pragma unroll
        for (int i = ty; i < 32; i += 8)
            dst[(size_t)(n0 + i) * CCH + k0 + tx] = (bf16)tile[tx][i];
        __syncthreads();
    } else {
        for (int i = tid; i < 1536; i += 256) {
            float v = (i < 512) ? bq[i] : (i < 1024) ? bk[i - 512] : bv[i - 1024];
            biasQKV[i] = v;
        }
    }
}

// Build per-block (mu, rstd) table for the 64 (b,g) groups from partials.
__device__ __forceinline__ void gn_table(char* smem, const float* __restrict__ statsP) {
    float* tbl = (float*)smem;                // 128 floats
    const int tid = threadIdx.x;
    if (tid < 64) {
        float S = 0.f, SS = 0.f;
        #pragma unroll
        for (int c = 0; c < 8; ++c) { S += statsP[tid * 16 + c]; SS += statsP[tid * 16 + 8 + c]; }
        float mu = S * (1.f / 65536.f);
        float rs = rsqrtf(SS * (1.f / 65536.f) - mu * mu + 1e-5f);
        tbl[tid * 2] = mu; tbl[tid * 2 + 1] = rs;
    }
    __syncthreads();
}

// gn unit: one 256-thread block's worth (256 float4 of [8192][128]).
__device__ __forceinline__ void gn_unit(
    char* smem, int w, const float* __restrict__ x,
    const float* __restrict__ gamma, const float* __restrict__ beta,
    bf16* __restrict__ xn) {
    const float* tbl = (const float*)smem;
    size_t idx = (size_t)w * 256 + threadIdx.x;
    int c4 = (int)(idx & 127);
    int b = (int)(idx >> 19);
    int bg = b * 32 + (c4 >> 2);
    float mu = tbl[bg * 2], rs = tbl[bg * 2 + 1];
    float4 v  = ((const float4*)x)[idx];
    float4 gm = ((const float4*)gamma)[c4];
    float4 bt = ((const float4*)beta)[c4];
    bf16x4 o;
    o[0] = (bf16)((v.x - mu) * rs * gm.x + bt.x);
    o[1] = (bf16)((v.y - mu) * rs * gm.y + bt.y);
    o[2] = (bf16)((v.z - mu) * rs * gm.z + bt.z);
    o[3] = (bf16)((v.w - mu) * rs * gm.w + bt.w);
    ((bf16x4*)xn)[idx] = o;
}

// vtrans unit: 64x64 transpose of qkv's v slice -> vT[b][c][s].
__device__ __forceinline__ void vtrans_unit(char* smem,
                                            const bf16* __restrict__ qkv,
                                            bf16* __restrict__ vT,
                                            int b, int s0, int c0) {
    bf16 (*tile)[65] = (bf16(*)[65])smem;     // 8320 B
    const int tx = threadIdx.x & 63;
    const int w = threadIdx.x >> 6;
    #pragma unroll
    for (int i = 0; i < 16; ++i) {
        int row = w + i * 4;
        tile[row][tx] = qkv[((size_t)b * SEQ + s0 + row) * 1536 + 1024 + c0 + tx];
    }
    __syncthreads();
    #pragma unroll
    for (int i = 0; i < 16; ++i) {
        int row = w + i * 4;
        vT[((size_t)b * CCH + c0 + row) * SEQ + s0 + tx] = tile[tx][row];
    }
    __syncthreads();
}

// ---------------------------------------------------------------------------
// Generalized bf16 B^T GEMM body (R4/R5 core): 128 x BN tile, BK=64, async
// global->LDS (16B), XOR-swizzled LDS (chunk ^= row&7), 16x16x32 MFMA.
//   C[m][n] = sum_k A[m][k] * Bt[n][k & bkmask]
// Epilogues: 0 bf16=acc+bias[n] | 1 bf16=exp(acc*scale)+lsum partials |
//            2 bf16=acc/l (l reduced post-K-loop in dead As space;
//              split-K=2 via bz) | 3 f32=acc+bias[n]+resid[m*512+n]
template <int EPI, int BN>
__device__ __forceinline__ void gemm2_body(
    char* smem, int bxi, int byi, int bzi,
    const bf16* __restrict__ A, long long aBatch, int lda,
    const bf16* __restrict__ Bt, long long bBatch, int ldb,
    void* __restrict__ Cout, long long cBatch, int ldc,
    int K, int bkmask, float scale,
    const float* __restrict__ bias, const float* __restrict__ resid,
    float* __restrict__ lsum, long long lsumBatch) {
    constexpr int JN = BN / 32;
    bf16* As = (bf16*)smem;                       // 16384 B
    bf16* Bs = (bf16*)(smem + 16384);             // up to 16384 B
    const int tid = threadIdx.x;
    const int lane = tid & 63;
    const int wave = tid >> 6;

    int zb = bzi, kc = 0;
    if constexpr (EPI == 2) { kc = zb & 1; zb >>= 1; }
    const long long m0 = (long long)bxi * 128;
    const long long n0 = (long long)byi * BN;
    const bf16* Ab = A + (long long)zb * aBatch + (EPI == 2 ? (long long)kc * 2048 : 0);
    const bf16* Bb = Bt + (long long)zb * bBatch + (EPI == 2 ? (long long)kc * 2048 : 0);

    const int wm = (wave & 1) * 64;
    const int wn = (wave >> 1) * (BN / 2);
    const int fm = lane & 15;
    const int q4 = lane >> 4;

    f32x4 acc[4][JN];
    #pragma unroll
    for (int i = 0; i < 4; ++i)
        #pragma unroll
        for (int j = 0; j < JN; ++j)
            acc[i][j] = (f32x4){0.f, 0.f, 0.f, 0.f};

    const int srow = tid >> 3;
    const int schunk = (tid & 7) ^ (srow & 7);

    for (int k0 = 0; k0 < K; k0 += 64) {
        const int kA = k0 + schunk * 8;
        const int kB = (k0 & bkmask) + schunk * 8;
        #pragma unroll
        for (int cb = 0; cb < 4; ++cb) {
            const bf16* g = Ab + (m0 + cb * 32 + srow) * (long long)lda + kA;
            __builtin_amdgcn_global_load_lds((const __attribute__((address_space(1))) void*)g,
                                             (__attribute__((address_space(3))) void*)&As[cb * 2048 + tid * 8], 16, 0, 0);
        }
        #pragma unroll
        for (int cb = 0; cb < BN / 32; ++cb) {
            const bf16* g = Bb + (n0 + cb * 32 + srow) * (long long)ldb + kB;
            __builtin_amdgcn_global_load_lds((const __attribute__((address_space(1))) void*)g,
                                             (__attribute__((address_space(3))) void*)&Bs[cb * 2048 + tid * 8], 16, 0, 0);
        }
        __syncthreads();
        #pragma unroll
        for (int kcc = 0; kcc < 2; ++kcc) {
            bf16x8 fa[4], fb[JN];
            #pragma unroll
            for (int i = 0; i < 4; ++i) {
                const int row = wm + i * 16 + fm;
                const int sw = ((kcc * 4 + q4) ^ (fm & 7)) * 8;
                fa[i] = *(const bf16x8*)&As[row * 64 + sw];
            }
            #pragma unroll
            for (int j = 0; j < JN; ++j) {
                const int row = wn + j * 16 + fm;
                const int sw = ((kcc * 4 + q4) ^ (fm & 7)) * 8;
                fb[j] = *(const bf16x8*)&Bs[row * 64 + sw];
            }
            #pragma unroll
            for (int i = 0; i < 4; ++i)
                #pragma unroll
                for (int j = 0; j < JN; ++j)
                    acc[i][j] = __builtin_amdgcn_mfma_f32_16x16x32_bf16(fa[i], fb[j], acc[i][j], 0, 0, 0);
        }
        __syncthreads();
    }

    // EPI 2: reduce 64 lsum partials -> lrow = 1/l, in the now-dead As space.
    float* lrow = (float*)(smem + 1024);
    if constexpr (EPI == 2) {
        float* lscr = (float*)smem;               // 1024 B
        const float* lsb = lsum + (long long)zb * lsumBatch + m0;
        const int row = tid & 127, h = tid >> 7;
        float s = 0.f;
        #pragma unroll
        for (int p = 0; p < 32; ++p)
            s += lsb[(long long)(h * 32 + p) * SEQ + row];
        lscr[tid] = s;
        __syncthreads();
        if (tid < 128) lrow[tid] = 1.f / (lscr[tid] + lscr[tid + 128]);
        __syncthreads();
    }

    // C/D layout: col = lane&15, row = (lane>>4)*4 + reg  [verified m89/m91]
    const int col = lane & 15;
    const int rowb = (lane >> 4) * 4;

    if constexpr (EPI == 1) {
        bf16* Pb = (bf16*)Cout + (long long)zb * cBatch;
        float* lsw = lsum + (long long)zb * lsumBatch
                   + ((long long)byi * 2 + (wave >> 1)) * SEQ;
        #pragma unroll
        for (int i = 0; i < 4; ++i) {
            float rs[4] = {0.f, 0.f, 0.f, 0.f};
            long long mg = m0 + wm + i * 16 + rowb;
            #pragma unroll
            for (int j = 0; j < JN; ++j) {
                long long ng = n0 + wn + j * 16 + col;
                #pragma unroll
                for (int r = 0; r < 4; ++r) {
                    float e = __expf(acc[i][j][r] * scale);
                    rs[r] += e;
                    Pb[(mg + r) * (long long)ldc + ng] = (bf16)e;
                }
            }
            #pragma unroll
            for (int r = 0; r < 4; ++r) {
                rs[r] += __shfl_xor(rs[r], 1);
                rs[r] += __shfl_xor(rs[r], 2);
                rs[r] += __shfl_xor(rs[r], 4);
                rs[r] += __shfl_xor(rs[r], 8);
            }
            if (col == 0) {
                #pragma unroll
                for (int r = 0; r < 4; ++r) lsw[mg + r] = rs[r];
            }
        }
    } else {
        #pragma unroll
        for (int i = 0; i < 4; ++i) {
            #pragma unroll
            for (int j = 0; j < JN; ++j) {
                long long mg = m0 + wm + i * 16 + rowb;
                long long ng = n0 + wn + j * 16 + col;
                #pragma unroll
                for (int r = 0; r < 4; ++r) {
                    float v = acc[i][j][r];
                    long long m = mg + r;
                    if constexpr (EPI == 0) {
                        ((bf16*)Cout)[m * (long long)ldc + ng] = (bf16)(v + bias[ng]);
                    } else if constexpr (EPI == 2) {
                        float inv = lrow[(int)(m - m0)];
                        ((bf16*)Cout)[(long long)zb * cBatch + m * (long long)ldc
                                      + kc * 512 + ng] = (bf16)(v * inv);
                    } else {
                        ((float*)Cout)[m * (long long)ldc + ng] =
                            v + bias[ng] + resid[m * CCH + ng];
                    }
                }
            }
        }
    }
}

// ---------------------------------------------------------------------------
// R12: 256x256 Z-order QK kernel. 512 thr / 8 waves (qm: 64-row band,
// qn: 32-col band of the active 128x128 quadrant). K=512 = 8 tiles of 64.
// LDS 128KB: lds[buf][A/B][256*64], chunk-XOR swizzle (pre-swizzled source).
// Phases per tile (Z-order): p0=(mh0,nh0) read fa(A0)+fbA(B0);
// p1=(mh0,nh1) read fbB(B1), hold fa; p2=(mh1,nh1) read fa(A1), hold fbB;
// p3=(mh1,nh0) hold fa+fbA (0 reads). 24 ds_read_b128/tile/wave (was 48).
// ONE s_barrier per phase. Stage slot order per tile-cycle [A0,B1,B0,A1]:
// slot overwrite-issue (for tile T+2, same buffer as T) is >=1 barrier after
// its last LDS read of tile T: A0 read p0 / issue p2(T); B1 p1 / p3(T);
// B0 p0 / p0(T+1); A1 p2 / p1(T+1). Counted vmcnt(4) only at tile boundary
// (2 half-tiles in flight), vmcnt(0) once at T==6. setprio around MFMA (T5).
// Epilogue: exp + P write + lsum partial (nt*4+qn) -> PV contract unchanged.
// ---------------------------------------------------------------------------
__global__ __launch_bounds__(512, 2) void k_qk256(
    const bf16* __restrict__ qkv, bf16* __restrict__ P,
    float* __restrict__ lsum, float scale) {
    __shared__ __align__(16) bf16 lds[2][2][256 * 64];   // [buf][A/B] 128 KB

    const int tid  = threadIdx.x;
    const int lane = tid & 63;
    const int wave = tid >> 6;            // 0..7
    const int qm = (wave >> 2) & 1;       // 64-row band within quadrant
    const int qn = wave & 3;              // 32-col band within quadrant
    const int fm = lane & 15;
    const int q4 = lane >> 4;

    // Block map: xcd = bid&7 owns an 8x8 tile chunk of one batch quadrant.
    const int bid = blockIdx.x;
    const int xcd = bid & 7, l = bid >> 3;
    const int bz = xcd >> 2, quad = xcd & 3;
    const int mt = (quad >> 1) * 8 + (l >> 3);
    const int nt = (quad & 1) * 8 + (l & 7);
    const long long m0 = (long long)mt * 256;
    const long long n0 = (long long)nt * 256;
    const bf16* Aq = qkv + (long long)bz * SEQ * 1536;        // q, lda=1536
    const bf16* Bk = Aq + 512;                                // k, ldb=1536

    // Staging: thread t covers row t>>3 (of 64-row group), chunk t&7.
    const int srow = tid >> 3;
    const int schunk = tid & 7;

    f32x4 acc[4][4][2];                   // [mh*2+nh][i][j]
    #pragma unroll
    for (int p = 0; p < 4; ++p)
        #pragma unroll
        for (int i = 0; i < 4; ++i)
            #pragma unroll
            for (int j = 0; j < 2; ++j)
                acc[p][i][j] = (f32x4){0.f, 0.f, 0.f, 0.f};

    // Stage half-tile h: tile th=h>>2, slot jj=h&3 in order [A0,B1,B0,A1].
    auto STAGE = [&](int h) {
        const int th = h >> 2, jj = h & 3;
        const int ab = (jj == 1 || jj == 2) ? 1 : 0;  // 0=A(q), 1=B(k)
        const int half = jj & 1;                      // jj: 0->A0,1->B1,2->B0,3->A1
        const bf16* src = ab ? Bk : Aq;
        const long long base0 = ab ? n0 : m0;
        const int kc = th * 64 + ((schunk ^ (srow & 7)) << 3);
        bf16* dst = &lds[th & 1][ab][(half * 128) * 64];
        #pragma unroll
        for (int c = 0; c < 2; ++c) {
            const bf16* g = src + (base0 + half * 128 + c * 64 + srow) * 1536 + kc;
            __builtin_amdgcn_global_load_lds(
                (const __attribute__((address_space(1))) void*)g,
                (__attribute__((address_space(3))) void*)&dst[c * 64 * 64 + tid * 8],
                16, 0, 0);
        }
    };

    // Prologue: stage h=0..5 (tile0 complete + tile1 A0,B1), wait tile0.
    #pragma unroll
    for (int h = 0; h < 6; ++h) STAGE(h);
    asm volatile("s_waitcnt vmcnt(4)" ::: "memory");
    __builtin_amdgcn_s_barrier();

    #pragma unroll
    for (int T = 0; T < 8; ++T) {
        const int bi = T & 1;
        bf16x8 fa[4][2], fbA[2][2], fbB[2][2];

        // ---- p0: (mh0, nh0) — read fa <- A0, fbA <- B0
        #pragma unroll
        for (int i = 0; i < 4; ++i) {
            const int R = qm * 64 + i * 16 + fm;
            #pragma unroll
            for (int s = 0; s < 2; ++s)
                fa[i][s] = *(const bf16x8*)
                    &lds[bi][0][R * 64 + ((((s << 2) + q4) ^ (fm & 7)) << 3)];
        }
        #pragma unroll
        for (int j = 0; j < 2; ++j) {
            const int R = qn * 32 + j * 16 + fm;
            #pragma unroll
            for (int s = 0; s < 2; ++s)
                fbA[j][s] = *(const bf16x8*)
                    &lds[bi][1][R * 64 + ((((s << 2) + q4) ^ (fm & 7)) << 3)];
        }
        if (T < 7) STAGE(T * 4 + 6);          // B0 of tile T+1 (other buffer)
        __builtin_amdgcn_s_setprio(1);
        #pragma unroll
        for (int i = 0; i < 4; ++i)
            #pragma unroll
            for (int j = 0; j < 2; ++j)
                #pragma unroll
                for (int s = 0; s < 2; ++s)
                    acc[0][i][j] = __builtin_amdgcn_mfma_f32_16x16x32_bf16(
                        fa[i][s], fbA[j][s], acc[0][i][j], 0, 0, 0);
        __builtin_amdgcn_s_setprio(0);
        __builtin_amdgcn_s_barrier();

        // ---- p1: (mh0, nh1) — read fbB <- B1; hold fa
        #pragma unroll
        for (int j = 0; j < 2; ++j) {
            const int R = 128 + qn * 32 + j * 16 + fm;
            #pragma unroll
            for (int s = 0; s < 2; ++s)
                fbB[j][s] = *(const bf16x8*)
                    &lds[bi][1][R * 64 + ((((s << 2) + q4) ^ (fm & 7)) << 3)];
        }
        if (T < 7) STAGE(T * 4 + 7);          // A1 of tile T+1 (other buffer)
        __builtin_amdgcn_s_setprio(1);
        #pragma unroll
        for (int i = 0; i < 4; ++i)
            #pragma unroll
            for (int j = 0; j < 2; ++j)
                #pragma unroll
                for (int s = 0; s < 2; ++s)
                    acc[1][i][j] = __builtin_amdgcn_mfma_f32_16x16x32_bf16(
                        fa[i][s], fbB[j][s], acc[1][i][j], 0, 0, 0);
        __builtin_amdgcn_s_setprio(0);
        __builtin_amdgcn_s_barrier();

        // ---- p2: (mh1, nh1) — read fa <- A1; hold fbB
        #pragma unroll
        for (int i = 0; i < 4; ++i) {
            const int R = 128 + qm * 64 + i * 16 + fm;
            #pragma unroll
            for (int s = 0; s < 2; ++s)
                fa[i][s] = *(const bf16x8*)
                    &lds[bi][0][R * 64 + ((((s << 2) + q4) ^ (fm & 7)) << 3)];
        }
        if (T < 6) STAGE(T * 4 + 8);          // A0 of tile T+2 (this buffer;
                                              // A0 last read at p0 — safe)
        __builtin_amdgcn_s_setprio(1);
        #pragma unroll
        for (int i = 0; i < 4; ++i)
            #pragma unroll
            for (int j = 0; j < 2; ++j)
                #pragma unroll
                for (int s = 0; s < 2; ++s)
                    acc[3][i][j] = __builtin_amdgcn_mfma_f32_16x16x32_bf16(
                        fa[i][s], fbB[j][s], acc[3][i][j], 0, 0, 0);
        __builtin_amdgcn_s_setprio(0);
        __builtin_amdgcn_s_barrier();

        // ---- p3: (mh1, nh0) — hold fa + fbA (0 reads)
        if (T < 6) STAGE(T * 4 + 9);          // B1 of tile T+2 (last read p1)
        __builtin_amdgcn_s_setprio(1);
        #pragma unroll
        for (int i = 0; i < 4; ++i)
            #pragma unroll
            for (int j = 0; j < 2; ++j)
                #pragma unroll
                for (int s = 0; s < 2; ++s)
                    acc[2][i][j] = __builtin_amdgcn_mfma_f32_16x16x32_bf16(
                        fa[i][s], fbA[j][s], acc[2][i][j], 0, 0, 0);
        __builtin_amdgcn_s_setprio(0);
        if (T < 6)
            asm volatile("s_waitcnt vmcnt(4)" ::: "memory");
        else if (T == 6)
            asm volatile("s_waitcnt vmcnt(0)" ::: "memory");
        if (T < 7) __builtin_amdgcn_s_barrier();
    }

    // Epilogue: P = exp(acc*scale), lsum partial idx = nt*4+qn (64/row).
    const int col16 = lane & 15;
    const int rowb = (lane >> 4) * 4;
    bf16* Pb = P + (long long)bz * SEQ * SEQ;
    float* lsw = lsum + (long long)bz * 64 * SEQ + (long long)(nt * 4 + qn) * SEQ;
    #pragma unroll
    for (int mh = 0; mh < 2; ++mh) {
        #pragma unroll
        for (int i = 0; i < 4; ++i) {
            float rs[4] = {0.f, 0.f, 0.f, 0.f};
            const long long mg = m0 + mh * 128 + qm * 64 + i * 16 + rowb;
            #pragma unroll
            for (int nh = 0; nh < 2; ++nh) {
                const int p = mh * 2 + nh;
                #pragma unroll
                for (int j = 0; j < 2; ++j) {
                    const long long ng = n0 + nh * 128 + qn * 32 + j * 16 + col16;
                    #pragma unroll
                    for (int r = 0; r < 4; ++r) {
                        float e = __expf(acc[p][i][j][r] * scale);
                        rs[r] += e;
                        Pb[(mg + r) * (long long)SEQ + ng] = (bf16)e;
                    }
                }
            }
            #pragma unroll
            for (int r = 0; r < 4; ++r) {
                rs[r] += __shfl_xor(rs[r], 1);
                rs[r] += __shfl_xor(rs[r], 2);
                rs[r] += __shfl_xor(rs[r], 4);
                rs[r] += __shfl_xor(rs[r], 8);
            }
            if (col16 == 0) {
                #pragma unroll
                for (int r = 0; r < 4; ++r) lsw[mg + r] = rs[r];
            }
        }
    }
}

// ---------------------------------------------------------------------------
// Per-phase kernels: R5 schedule + R9 XCD maps, exact 1D grids.
__global__ __launch_bounds__(256) void k_prep(
    const float* x, const float* Wq, const float* Wk, const float* Wv,
    const float* Wp, const float* bq, const float* bk, const float* bv,
    float* statsP, bf16* WqkvT, bf16* WpT, float* biasQKV) {
    __shared__ __align__(16) char smem[4352];
    prep_unit(smem, blockIdx.x, x, Wq, Wk, Wv, Wp, bq, bk, bv,
              statsP, WqkvT, WpT, biasQKV);
}

__global__ __launch_bounds__(256) void k_gn(
    const float* x, const float* statsP, const float* gamma,
    const float* beta, bf16* xn) {
    __shared__ __align__(16) char smem[512];
    gn_table(smem, statsP);
    gn_unit(smem, blockIdx.x, x, gamma, beta, xn);
}

// Phase 3: qkv = xn @ WqkvT^T + bias. 768 blocks; XCD (w&7) owns 8Mx12N.
__global__ __launch_bounds__(256, 2) void k_qkv_m(
    const bf16* xn, const bf16* WqkvT, bf16* qkv, const float* biasQKV) {
    __shared__ __align__(16) char smem[SMEM_BYTES];
    int w = blockIdx.x, l = w >> 3;
    gemm2_body<0, 128>(smem, (w & 7) * 8 + l / 12, l % 12, 0,
                       xn, 0, CCH, WqkvT, 0, CCH, qkv, 0, 1536,
                       CCH, NOMASK, 1.f, biasQKV, nullptr, nullptr, 0);
}

// v transpose: 1024 blocks.
__global__ __launch_bounds__(256, 2) void k_vtrans_m(const bf16* qkv, bf16* vT) {
    __shared__ __align__(16) char smem[8448];
    int w = blockIdx.x, b = w >> 9, r = w & 511;
    vtrans_unit(smem, qkv, vT, b, (r >> 3) * 64, (r & 7) * 64);
}

// Phase 5 PV: 1024 blocks; 8 N-tiles of one 0.5MB P strip on XCD (w&7).
__global__ __launch_bounds__(256, 2) void k_pv_m(
    const bf16* P, const bf16* vT, bf16* o2, float* lsum) {
    __shared__ __align__(16) char smem[SMEM_BYTES];
    int w = blockIdx.x, l = w >> 3;
    int S = (w & 7) * 16 + (l >> 3);
    gemm2_body<2, 64>(smem, S & 31, l & 7, S >> 5,
                      P, (long long)SEQ * SEQ, SEQ,
                      vT, (long long)CCH * SEQ, SEQ,
                      o2, (long long)SEQ * 1024, 1024,
                      2048, NOMASK, 1.f, nullptr, nullptr,
                      lsum, 64LL * SEQ);
}

// Phase 6 proj: 512 blocks; XCD (w&7) owns 8 o2-strips x 8 N.
__global__ __launch_bounds__(256, 2) void k_proj_m(
    const bf16* o2, const bf16* WpT, float* out, const float* bp,
    const float* x) {
    __shared__ __align__(16) char smem[SMEM_BYTES];
    int w = blockIdx.x, l = w >> 3;
    gemm2_body<3, 64>(smem, (w & 7) * 8 + (l >> 3), l & 7, 0,
                      o2, 0, 1024, WpT, 0, CCH, out, 0, CCH,
                      1024, 511, 1.f, bp, x, nullptr, 0);
}

// Legacy templated wrappers (small-workspace fallback path).
template <int EPI, int BN>
__global__ __launch_bounds__(256, 2) void k_gemm2(
    const bf16* A, long long aBatch, int lda,
    const bf16* Bt, long long bBatch, int ldb,
    void* Cout, long long cBatch, int ldc,
    int K, int bkmask, float scale,
    const float* bias, const float* resid,
    float* lsum, long long lsumBatch) {
    __shared__ __align__(16) char smem[SMEM_BYTES];
    gemm2_body<EPI, BN>(smem, blockIdx.x, blockIdx.y, blockIdx.z,
                        A, aBatch, lda, Bt, bBatch, ldb, Cout, cBatch, ldc,
                        K, bkmask, scale, bias, resid, lsum, lsumBatch);
}

__global__ __launch_bounds__(256, 2) void k_qk_vtrans(
    const bf16* qkv, bf16* vT, bf16* P, float* lsum, float scale,
    int vtBlocks, long long qkBatch, long long pBatch, long long lsumBatch) {
    __shared__ __align__(16) char smem[SMEM_BYTES];
    const int bid = blockIdx.x;
    if (bid < vtBlocks) {
        int b = bid >> 9, r = bid & 511;
        vtrans_unit(smem, qkv, vT, b, (r >> 3) * 64, (r & 7) * 64);
    } else {
        int q = bid - vtBlocks;
        int bz = q >> 10, r = q & 1023;
        gemm2_body<1, 128>(smem, r >> 5, r & 31, bz,
                           qkv, qkBatch, 1536, qkv + 512, qkBatch, 1536,
                           P, pBatch, SEQ, CCH, NOMASK, scale,
                           nullptr, nullptr, lsum, lsumBatch);
    }
}

// ---------------------------------------------------------------------------
extern "C" void kernel_launch(void* const* d_in, const int* in_sizes, int n_in,
                              void* d_out, int out_size, void* d_ws, size_t ws_size,
                              hipStream_t stream) {
    const float* x     = (const float*)d_in[0];
    const float* gamma = (const float*)d_in[1];
    const float* beta  = (const float*)d_in[2];
    const float* Wq    = (const float*)d_in[3];
    const float* bq    = (const float*)d_in[4];
    const float* Wk    = (const float*)d_in[5];
    const float* bk    = (const float*)d_in[6];
    const float* Wv    = (const float*)d_in[7];
    const float* bv    = (const float*)d_in[8];
    const float* Wp    = (const float*)d_in[9];
    const float* bp    = (const float*)d_in[10];
    float* out = (float*)d_out;

    // Workspace (aliased; lifetimes: xn dead after QKV, q/k dead after QK)
    constexpr size_t OFF_STATS = 0;          // 4 KB (statsP partials, 1024 f32)
    constexpr size_t OFF_BIAS  = 4096;       // 6 KB
    constexpr size_t OFF_WQKVT = 12288;      // 1.57 MB
    constexpr size_t OFF_WPT   = 1585152;    // 0.5 MB [512][512]
    constexpr size_t OFF_XN    = 2109440;    // 8.39 MB; dead after QKV ->
    constexpr size_t OFF_LSUM  = OFF_XN;     //   2.10 MB [2][64][4096] f32
    constexpr size_t OFF_QKV   = 10498048;   // 25.17 MB; q,k dead after QK ->
    constexpr size_t OFF_O2    = OFF_QKV;    //   16.78 MB [8192][1024] bf16
    constexpr size_t OFF_VT    = 35663872;   // 8.39 MB [2][512][4096]
    constexpr size_t OFF_P     = 44052480;   // 67.1 MB (full) / 33.6 MB (per-batch)
    constexpr size_t NEED_FULL = OFF_P + (size_t)NBAT * SEQ * SEQ * 2;

    char* ws = (char*)d_ws;
    float* statsP  = (float*)(ws + OFF_STATS);
    float* biasQKV = (float*)(ws + OFF_BIAS);
    bf16*  WqkvT   = (bf16*)(ws + OFF_WQKVT);
    bf16*  WpT     = (bf16*)(ws + OFF_WPT);
    bf16*  xn      = (bf16*)(ws + OFF_XN);
    float* lsum    = (float*)(ws + OFF_LSUM);
    bf16*  qkv     = (bf16*)(ws + OFF_QKV);
    bf16*  o2      = (bf16*)(ws + OFF_O2);
    bf16*  vT      = (bf16*)(ws + OFF_VT);
    bf16*  P       = (bf16*)(ws + OFF_P);

    const float scale = 0.044194173824159216f;  // 1/sqrt(512)
    const bool full = ws_size >= NEED_FULL;

    if (full) {
        k_prep<<<1537, 256, 0, stream>>>(x, Wq, Wk, Wv, Wp, bq, bk, bv,
                                         statsP, WqkvT, WpT, biasQKV);
        k_gn<<<4096, 256, 0, stream>>>(x, statsP, gamma, beta, xn);
        k_qkv_m<<<768, 256, 0, stream>>>(xn, WqkvT, qkv, biasQKV);
        k_vtrans_m<<<1024, 256, 0, stream>>>(qkv, vT);
        k_qk256<<<512, 512, 0, stream>>>(qkv, P, lsum, scale);   // R12
        k_pv_m<<<1024, 256, 0, stream>>>(P, vT, o2, lsum);
        k_proj_m<<<512, 256, 0, stream>>>(o2, WpT, out, bp, x);
    } else {
        // Small-workspace fallback (per-batch P), unchanged.
        k_prep<<<1537, 256, 0, stream>>>(x, Wq, Wk, Wv, Wp, bq, bk, bv,
                                         statsP, WqkvT, WpT, biasQKV);
        k_gn<<<4096, 256, 0, stream>>>(x, statsP, gamma, beta, xn);
        k_gemm2<0, 128><<<dim3(64, 12, 1), 256, 0, stream>>>(
            xn, 0, CCH, WqkvT, 0, CCH, qkv, 0, 1536,
            CCH, NOMASK, 1.f, biasQKV, nullptr, nullptr, 0);
        for (int b = 0; b < NBAT; ++b) {
            const bf16* qb = qkv + (long long)b * SEQ * 1536;
            k_qk_vtrans<<<1536, 256, 0, stream>>>(
                qb, vT + (long long)b * CCH * SEQ, P,
                lsum + (long long)b * 64 * SEQ, scale, 512, 0, 0, 0);
            k_gemm2<2, 128><<<dim3(32, 4, 2), 256, 0, stream>>>(
                P, 0, SEQ, vT + (long long)b * CCH * SEQ, 0, SEQ,
                o2 + (long long)b * SEQ * 1024, 0, 1024,
                2048, NOMASK, 1.f, nullptr, nullptr,
                lsum + (long long)b * 64 * SEQ, 0);
        }
        k_gemm2<3, 64><<<dim3(64, 8, 1), 256, 0, stream>>>(
            o2, 0, 1024, WpT, 0, CCH, out, 0, CCH,
            1024, 511, 1.f, bp, x, nullptr, 0);
    }
}